// Round 16
// baseline (5442.493 us; speedup 1.0000x reference)
//
#include <hip/hip_runtime.h>

#define SEQL   512
#define HID    2048
#define NCLS   10

typedef _Float16 f16x8 __attribute__((ext_vector_type(8)));
typedef float    f32x4 __attribute__((ext_vector_type(4)));

__device__ __forceinline__ float fast_tanh(float v) {
    float e = __expf(2.0f * v);
    return 1.0f - 2.0f / (e + 1.0f);
}

// Pack whh (fp32 row-major [col][k]) into fp16 MFMA fragments, member-major.
// Member m owns 256 frags (4 jobs x 64). Job j=(cbb=j&1, kq2=j>>1) covers
// tiles {cbb, 2+cbb} x ksts [kq2*32, kq2*32+32).
//   local 0..95  (LDS, 24/job): sub<12 -> tile cbb, kst kq2*32+sub
//                               sub>=12 -> tile 2+cbb, kst kq2*32+(sub-12)
//   local 96..255 (regs, 40/job): f<20 -> tile cbb,   kst kq2*32+12+f
//                                 f>=20 -> tile 2+cbb, kst kq2*32+12+(f-20)
__global__ void pack_w_kernel(const float* __restrict__ w, _Float16* __restrict__ o) {
    const int fid = blockIdx.x * 256 + threadIdx.x;   // 0..524287
    const int ln    = fid & 63;
    const int frag  = fid >> 6;
    const int m     = frag >> 8;
    const int local = frag & 255;
    int tile, kst;
    if (local < 96) {
        const int j = local / 24, sub = local % 24;
        const int cbb = j & 1, kq2 = j >> 1;
        tile = (sub < 12) ? cbb : 2 + cbb;
        kst  = kq2 * 32 + (sub % 12);
    } else {
        const int l2 = local - 96;
        const int j = l2 / 40, f = l2 % 40;
        const int cbb = j & 1, kq2 = j >> 1;
        tile = (f < 20) ? cbb : 2 + cbb;
        kst  = kq2 * 32 + 12 + (f % 20);
    }
    const int col = m * 64 + tile * 16 + (ln & 15);
    const int k0  = kst * 32 + (ln >> 4) * 8;
    const float* src = w + (size_t)col * HID + k0;
    f16x8 v;
    #pragma unroll
    for (int i = 0; i < 8; ++i) v[i] = (_Float16)src[i];
    *(f16x8*)(o + (size_t)fid * 8) = v;
}

__global__ void __launch_bounds__(512, 2)
rnn_main(const float* __restrict__ x, const float* __restrict__ whx,
         const _Float16* __restrict__ Wp, const float* __restrict__ bh,
         const float* __restrict__ wph, const float* __restrict__ bp,
         _Float16* __restrict__ h0, _Float16* __restrict__ h1,
         unsigned* __restrict__ ctr, float* __restrict__ out)
{
    // 96 KiB pinned W (LDS frags 0..95): slot = local*64 + lane
    __shared__ uint4 ldsW[6144];
    // 32 KiB partials, double-buffered by t-parity:
    //   slot = (((par*2+half)*2+kq2)*4 + tile)*64 + lane
    __shared__ f32x4 ldsP[2048];
    __shared__ unsigned s_mslot;

    const int tid = threadIdx.x;

    // physical XCD id -> group; member slot via allocator (32 WGs/XCD: 1 WG/CU)
    int xcc;
    asm volatile("s_getreg_b32 %0, hwreg(HW_REG_XCC_ID)" : "=s"(xcc));
    const int g = xcc & 7;
    unsigned* alloc = ctr + g * 64;
    unsigned* flgA  = ctr + 512 + g * 1024;           // 32 member flags, 128B stride
    unsigned* flgB  = ctr + 512 + 8192 + g * 1024;    // half-B flags
    if (tid == 0)
        s_mslot = __hip_atomic_fetch_add(alloc, 1u, __ATOMIC_RELAXED, __HIP_MEMORY_SCOPE_WORKGROUP);
    __syncthreads();
    const int m = (int)s_mslot;              // 0..31
    const int rowbase = g * 32;              // rows [rowbase,+16)=A, [+16,+32)=B
    const int colbase = m * 64;

    const int lane = tid & 63;
    const int wv   = tid >> 6;               // wave 0..7
    const int half = wv >> 2;                // 0: half A (waves 0-3), 1: half B (4-7)
    const int job  = wv & 3;                 // (cbb, kq2) and reducer tile id
    const int cbb  = job & 1;
    const int kq2  = job >> 1;

    const uint4* P4 = (const uint4*)Wp;

    // ---- stage LDS W frags (member's first 96 frags, contiguous) ----
    for (int s5 = tid; s5 < 6144; s5 += 512)
        ldsW[s5] = P4[m * 16384 + s5];

    // ---- step 0: h = tanh(x[:,0]*whx + bh) for all 32 rows ----
    for (int i = tid; i < 32 * 64; i += 512) {
        const int r = i >> 6, c = i & 63;
        const int b = rowbase + r, jj = colbase + c;
        h0[(size_t)b * HID + jj] = (_Float16)fast_tanh(x[(size_t)b * SEQL] * whx[jj] + bh[jj]);
    }

    // ---- pin this wave's 40 reg frags (160 VGPR/AGPR; shared set with the
    //      other half's wave of the same job, loaded redundantly) ----
    const uint4* R4 = P4 + m * 16384 + (96 + job * 40) * 64 + lane;
    f16x8 bReg[40];
    #pragma unroll
    for (int f = 0; f < 40; ++f) bReg[f] = *(const f16x8*)&R4[f * 64];

    // reducer job: (half, tile=job)
    const int ecol = colbase + job * 16 + (lane & 15);
    const float wxc = whx[ecol], bbc = bh[ecol];
    const int erow = rowbase + half * 16 + (lane >> 4) * 4;

    // A-operand: row = rowbase + half*16 + (lane&15), kst i -> kq2*1024 + i*32 + (lane>>4)*8
    const size_t aoff = (size_t)(rowbase + half * 16 + (lane & 15)) * HID
                      + kq2 * 1024 + (lane >> 4) * 8;
    const uint4* bl = &ldsW[job * 24 * 64 + lane];     // low: bl[i*64], high: bl[(12+i)*64]
    unsigned* myflg = (half ? flgB : flgA) + m * 32;
    const unsigned* pollp = (half ? flgB : flgA) + (lane & 31) * 32;

    // prologue arrive: drain step-0 stores + staging, post both flag sets (+4)
    __syncthreads();
    if (tid == 0) {
        __hip_atomic_fetch_add(flgA + m * 32, 4u, __ATOMIC_RELAXED, __HIP_MEMORY_SCOPE_WORKGROUP);
        __hip_atomic_fetch_add(flgB + m * 32, 4u, __ATOMIC_RELAXED, __HIP_MEMORY_SCOPE_WORKGROUP);
    }

    for (int t = 1; t < SEQL; ++t) {
        const _Float16* hs = (t & 1) ? h0 : h1;
        _Float16*       hd = (t & 1) ? h1 : h0;
        const unsigned tgt = 4u * (unsigned)t;
        const int par = t & 1;
        f32x4* Pw = &ldsP[((par * 2 + half) * 2 + kq2) * 4 * 64];       // writer base
        f32x4* Pr = &ldsP[(par * 2 + half) * 2 * 4 * 64];               // reducer base

        // keep reg-pinned frags materialized (stop reload/sinking)
        #pragma unroll
        for (int f = 0; f < 40; ++f) asm volatile("" : "+v"(bReg[f]));

        // epilogue x-values: stale-safe input, issue before the poll
        float xv[4];
        #pragma unroll
        for (int r = 0; r < 4; ++r)
            xv[r] = x[(size_t)(erow + r) * SEQL + t];

        // poll own half's 32 member flags (agent scope = L1-bypass, local L2);
        // the other half's waves poll concurrently on the same SIMDs
        {
            unsigned v;
            do {
                v = __hip_atomic_load(pollp, __ATOMIC_RELAXED, __HIP_MEMORY_SCOPE_AGENT);
            } while (!__all((int)(v >= tgt)));
        }
        asm volatile("buffer_inv sc0" ::: "memory");   // this CU's L1 -> fresh h via L2

        // ---- compute this wave's partials: tiles {cbb, 2+cbb} x 32 ksts ----
        const _Float16* ap = hs + aoff;
        f32x4 accLo = {0.f,0.f,0.f,0.f}, accHi = accLo;
        #pragma unroll
        for (int c = 0; c < 4; ++c) {
            f16x8 av[8];
            #pragma unroll
            for (int u = 0; u < 8; ++u)
                av[u] = *(const f16x8*)(ap + (c * 8 + u) * 32);
            #pragma unroll
            for (int u = 0; u < 8; ++u) {
                const int i = c * 8 + u;
                const f16x8 bLo = (i < 12) ? *(const f16x8*)&bl[i * 64]        : bReg[i - 12];
                const f16x8 bHi = (i < 12) ? *(const f16x8*)&bl[(12 + i) * 64] : bReg[20 + i - 12];
                accLo = __builtin_amdgcn_mfma_f32_16x16x32_f16(av[u], bLo, accLo, 0, 0, 0);
                accHi = __builtin_amdgcn_mfma_f32_16x16x32_f16(av[u], bHi, accHi, 0, 0, 0);
            }
        }
        Pw[cbb * 64 + lane]       = accLo;
        Pw[(2 + cbb) * 64 + lane] = accHi;

        __syncthreads();   // partials of both kq2 halves visible (couples halves only here)

        // ---- reduce own (half, tile=job): 2 kq2-partials, epilogue, store, flag ----
        {
            const f32x4 s = Pr[job * 64 + lane] + Pr[(4 + job) * 64 + lane];
            #pragma unroll
            for (int r = 0; r < 4; ++r) {
                const int br = erow + r;
                hd[(size_t)br * HID + ecol] =
                    (_Float16)fast_tanh(s[r] + xv[r] * wxc + bbc);
            }
            asm volatile("s_waitcnt vmcnt(0)" ::: "memory");   // wave's stores at L2
            if (lane == 0)
                __hip_atomic_fetch_add(myflg, 1u, __ATOMIC_RELAXED, __HIP_MEMORY_SCOPE_WORKGROUP);
        }
        // no second barrier: next step writes the other parity's ldsP bank
    }

    // final release: both halves' t=511 stores visible, then L1 inv
    {
        const unsigned tgt = 4u * (unsigned)SEQL;
        const unsigned* pA = flgA + (lane & 31) * 32;
        const unsigned* pB = flgB + (lane & 31) * 32;
        unsigned v;
        do {
            v = __hip_atomic_load(pA, __ATOMIC_RELAXED, __HIP_MEMORY_SCOPE_AGENT);
        } while (!__all((int)(v >= tgt)));
        do {
            v = __hip_atomic_load(pB, __ATOMIC_RELAXED, __HIP_MEMORY_SCOPE_AGENT);
        } while (!__all((int)(v >= tgt)));
    }
    asm volatile("buffer_inv sc0" ::: "memory");

    // ---- projection: p = h_last @ wph.T + bp (member m -> row rowbase+m) ----
    const int brow = rowbase + m;
    const _Float16* hp = h1 + (size_t)brow * HID + lane * 32;
    for (int c = wv; c < NCLS; c += 8) {
        const float* wp = wph + (size_t)c * HID + lane * 32;
        float psum = 0.f;
        #pragma unroll
        for (int i = 0; i < 32; ++i) psum += (float)hp[i] * wp[i];
        #pragma unroll
        for (int off = 32; off >= 1; off >>= 1) psum += __shfl_xor(psum, off, 64);
        if (lane == 0) out[brow * NCLS + c] = psum + bp[c];
    }
}

extern "C" void kernel_launch(void* const* d_in, const int* in_sizes, int n_in,
                              void* d_out, int out_size, void* d_ws, size_t ws_size,
                              hipStream_t stream) {
    const float* x   = (const float*)d_in[0];
    const float* whx = (const float*)d_in[1];
    const float* whh = (const float*)d_in[2];
    const float* bh  = (const float*)d_in[3];
    const float* wph = (const float*)d_in[4];
    const float* bp  = (const float*)d_in[5];
    float* out = (float*)d_out;

    char* ws = (char*)d_ws;
    _Float16* Wp  = (_Float16*)ws;                         // 8 MiB packed whh fp16
    _Float16* h0  = (_Float16*)(ws + (size_t)(8u << 20));  // 1 MiB  h buffer A
    _Float16* h1  = (_Float16*)(ws + (size_t)(9u << 20));  // 1 MiB  h buffer B
    unsigned* ctr = (unsigned*)(ws + (size_t)(10u << 20)); // 68 KiB alloc + 2x flags

    hipMemsetAsync(ctr, 0, (512 + 2 * 8 * 1024) * sizeof(unsigned), stream);
    pack_w_kernel<<<dim3(2048), dim3(256), 0, stream>>>(whh, Wp);

    void* args[] = { (void*)&x, (void*)&whx, (void*)&Wp, (void*)&bh, (void*)&wph,
                     (void*)&bp, (void*)&h0, (void*)&h1, (void*)&ctr, (void*)&out };
    hipLaunchCooperativeKernel((const void*)rnn_main, dim3(256), dim3(512),
                               args, 0, stream);
}

// Round 17
// 4379.271 us; speedup vs baseline: 1.2428x; 1.2428x over previous
//
#include <hip/hip_runtime.h>

#define SEQL   512
#define HID    2048
#define NCLS   10

typedef _Float16 f16x8 __attribute__((ext_vector_type(8)));
typedef float    f32x4 __attribute__((ext_vector_type(4)));

__device__ __forceinline__ float fast_tanh(float v) {
    float e = __expf(2.0f * v);
    return 1.0f - 2.0f / (e + 1.0f);
}

// Pack whh (fp32 row-major [col][k]) into fp16 MFMA fragments, two regions:
//   P [0,4MiB):  member-major pinned cols [colbase, colbase+32), all K -> LDS
//   R [4MiB,8MiB): per-wave pinned cols [colbase+32, colbase+64):
//     wave j holds col-block cbb=j&1 (16 cols), kst-quarter kq=j>>1 (16 ksts)
__global__ void pack_w_kernel(const float* __restrict__ w, _Float16* __restrict__ o) {
    const int fid = blockIdx.x * 256 + threadIdx.x;   // 0..524287
    int col, k0;
    if (fid < 262144) {                 // P: m(5b) | tile(1b) | kst(6b) | ln(6b)
        const int m = fid >> 13, s5 = fid & 8191;
        const int tile = s5 >> 12, kst = (s5 >> 6) & 63, ln = s5 & 63;
        col = m * 64 + tile * 16 + (ln & 15);
        k0  = kst * 32 + (ln >> 4) * 8;
    } else {                            // R: m(5b) | j(3b) | f(4b) | ln(6b)
        const int q = fid - 262144;
        const int m = q >> 13, r = q & 8191;
        const int j = r >> 10, f = (r >> 6) & 15, ln = r & 63;
        col = m * 64 + 32 + (j & 1) * 16 + (ln & 15);
        k0  = ((j >> 1) * 16 + f) * 32 + (ln >> 4) * 8;
    }
    const float* src = w + (size_t)col * HID + k0;
    f16x8 v;
    #pragma unroll
    for (int i = 0; i < 8; ++i) v[i] = (_Float16)src[i];
    *(f16x8*)(o + (size_t)fid * 8) = v;
}

__global__ void __launch_bounds__(512, 2)
rnn_main(const float* __restrict__ x, const float* __restrict__ whx,
         const _Float16* __restrict__ Wp, const float* __restrict__ bh,
         const float* __restrict__ wph, const float* __restrict__ bp,
         _Float16* __restrict__ h0, _Float16* __restrict__ h1,
         unsigned* __restrict__ ctr, float* __restrict__ out)
{
    // 128 KiB pinned W cols [colbase,colbase+32): slot(tile,kst,lane)
    __shared__ uint4 ldsW[8192];
    // 16 KiB partial buffer: slot = (tile tj 0..3)*4 + kq, tj = ecls*2 + ecbb
    __shared__ f32x4 ldsR[16 * 64];
    __shared__ unsigned s_mslot;

    const int tid = threadIdx.x;

    // physical XCD id -> group; member slot via allocator (32 WGs/XCD: 1 WG/CU)
    int xcc;
    asm volatile("s_getreg_b32 %0, hwreg(HW_REG_XCC_ID)" : "=s"(xcc));
    const int g = xcc & 7;
    unsigned* alloc = ctr + g * 64;
    unsigned* flgA  = ctr + 512 + g * 1024;           // 32 member flags, 128B stride
    unsigned* flgB  = ctr + 512 + 8192 + g * 1024;    // sub-batch B flags
    if (tid == 0)
        s_mslot = __hip_atomic_fetch_add(alloc, 1u, __ATOMIC_RELAXED, __HIP_MEMORY_SCOPE_WORKGROUP);
    __syncthreads();
    const int m = (int)s_mslot;              // 0..31
    unsigned* myflgA = flgA + m * 32;
    unsigned* myflgB = flgB + m * 32;
    const int rowbase = g * 32;              // rows [rowbase,+16)=A, [+16,+32)=B
    const int colbase = m * 64;

    const int lane = tid & 63;
    const int j    = tid >> 6;        // wave 0..7
    const int cbb  = j & 1;           // col-16-block (both classes)
    const int kq   = j >> 1;          // kst quarter 0..3

    const uint4* P4 = (const uint4*)Wp;

    // ---- pin P (cols colbase..+32) into LDS ----
    for (int s5 = tid; s5 < 8192; s5 += 512)
        ldsW[s5] = P4[m * 8192 + s5];

    // ---- step 0: h = tanh(x[:,0]*whx + bh) for all 32 rows ----
    for (int i = tid; i < 32 * 64; i += 512) {
        const int r = i >> 6, c = i & 63;
        const int b = rowbase + r, jj = colbase + c;
        h0[(size_t)b * HID + jj] = (_Float16)fast_tanh(x[(size_t)b * SEQL] * whx[jj] + bh[jj]);
    }

    // ---- pin this wave's 16 R-frags (64 VGPR) for all 512 steps ----
    const uint4* R4 = P4 + 262144 + m * 8192 + j * 1024 + lane;
    f16x8 bR[16];
    #pragma unroll
    for (int f = 0; f < 16; ++f) bR[f] = *(const f16x8*)&R4[f * 64];

    // reducer role: waves 0..3 own sub-batch A epilogue, 4..7 own B
    const int tj   = (j < 4) ? j : j - 4;          // tile 0..3 = ecls*2 + ecbb
    const int ecls = tj >> 1, ecbb = tj & 1;
    const int ecol = colbase + ecls * 32 + ecbb * 16 + (lane & 15);
    const float wxc = whx[ecol], bbc = bh[ecol];
    const int eroff = (lane >> 4) * 4;             // + sub_rowbase + r
    const int rdbase = tj * 4;

    // A-operand geometry: row = sub_rowbase + (lane&15), k = kq*512 + f*32 + (lane>>4)*8
    const size_t aoffA = (size_t)(rowbase + (lane & 15)) * HID + kq * 512 + (lane >> 4) * 8;
    const size_t aoffB = aoffA + (size_t)16 * HID;
    const uint4* bl = &ldsW[cbb * 4096 + kq * 1024 + lane];
    const unsigned* pollA = flgA + (lane & 31) * 32;
    const unsigned* pollB = flgB + (lane & 31) * 32;

    // prologue arrive: syncthreads drains all step-0 h stores, then post both flags
    __syncthreads();
    if (tid == 0) {
        __hip_atomic_fetch_add(myflgA, 4u, __ATOMIC_RELAXED, __HIP_MEMORY_SCOPE_WORKGROUP);
        __hip_atomic_fetch_add(myflgB, 4u, __ATOMIC_RELAXED, __HIP_MEMORY_SCOPE_WORKGROUP);
    }

    for (int t = 1; t < SEQL; ++t) {
        const _Float16* hs = (t & 1) ? h0 : h1;
        _Float16*       hd = (t & 1) ? h1 : h0;
        const unsigned tgt = 4u * (unsigned)t;

        // keep reg-pinned fragments materialized
        #pragma unroll
        for (int f = 0; f < 16; ++f) asm volatile("" : "+v"(bR[f]));

        // ================= sub-step A (rows rowbase..+16, reducers j<4) ======
        {
            float xv[4];
            if (j < 4) {
                #pragma unroll
                for (int r = 0; r < 4; ++r)
                    xv[r] = x[(size_t)(rowbase + eroff + r) * SEQL + t];
            }
            // poll A flags (agent scope = L1-bypass, local-L2 read)
            unsigned v;
            do {
                v = __hip_atomic_load(pollA, __ATOMIC_RELAXED, __HIP_MEMORY_SCOPE_AGENT);
            } while (!__all((int)(v >= tgt)));
            asm volatile("buffer_inv sc0" ::: "memory");   // fresh h via L2

            f16x8 av[16];
            #pragma unroll
            for (int f = 0; f < 16; ++f)
                av[f] = *(const f16x8*)(hs + aoffA + f * 32);

            f32x4 aL = {0.f,0.f,0.f,0.f}, aR = aL;
            #pragma unroll
            for (int f = 0; f < 16; ++f) {
                const f16x8 bLf = *(const f16x8*)&bl[f * 64];
                aL = __builtin_amdgcn_mfma_f32_16x16x32_f16(av[f], bLf,   aL, 0, 0, 0);
                aR = __builtin_amdgcn_mfma_f32_16x16x32_f16(av[f], bR[f], aR, 0, 0, 0);
            }

            __syncthreads();   // prior sub-step's ldsR readers done
            ldsR[(cbb * 4 + kq) * 64 + lane]       = aL;   // L tiles: tj = cbb
            ldsR[((2 + cbb) * 4 + kq) * 64 + lane] = aR;   // R tiles: tj = 2+cbb
            __syncthreads();

            if (j < 4) {
                const f32x4 s = ldsR[(rdbase + 0) * 64 + lane] + ldsR[(rdbase + 1) * 64 + lane]
                              + ldsR[(rdbase + 2) * 64 + lane] + ldsR[(rdbase + 3) * 64 + lane];
                #pragma unroll
                for (int r = 0; r < 4; ++r) {
                    const int br = rowbase + eroff + r;
                    hd[(size_t)br * HID + ecol] =
                        (_Float16)fast_tanh(s[r] + xv[r] * wxc + bbc);
                }
                asm volatile("s_waitcnt vmcnt(0)" ::: "memory");  // wave's stores at L2
                if (lane == 0)
                    __hip_atomic_fetch_add(myflgA, 1u, __ATOMIC_RELAXED, __HIP_MEMORY_SCOPE_WORKGROUP);
            }
        }

        // ================= sub-step B (rows rowbase+16..+32, reducers j>=4) ==
        {
            float xv[4];
            if (j >= 4) {
                #pragma unroll
                for (int r = 0; r < 4; ++r)
                    xv[r] = x[(size_t)(rowbase + 16 + eroff + r) * SEQL + t];
            }
            unsigned v;
            do {
                v = __hip_atomic_load(pollB, __ATOMIC_RELAXED, __HIP_MEMORY_SCOPE_AGENT);
            } while (!__all((int)(v >= tgt)));
            asm volatile("buffer_inv sc0" ::: "memory");

            f16x8 av[16];
            #pragma unroll
            for (int f = 0; f < 16; ++f)
                av[f] = *(const f16x8*)(hs + aoffB + f * 32);

            f32x4 aL = {0.f,0.f,0.f,0.f}, aR = aL;
            #pragma unroll
            for (int f = 0; f < 16; ++f) {
                const f16x8 bLf = *(const f16x8*)&bl[f * 64];
                aL = __builtin_amdgcn_mfma_f32_16x16x32_f16(av[f], bLf,   aL, 0, 0, 0);
                aR = __builtin_amdgcn_mfma_f32_16x16x32_f16(av[f], bR[f], aR, 0, 0, 0);
            }

            __syncthreads();
            ldsR[(cbb * 4 + kq) * 64 + lane]       = aL;
            ldsR[((2 + cbb) * 4 + kq) * 64 + lane] = aR;
            __syncthreads();

            if (j >= 4) {
                const f32x4 s = ldsR[(rdbase + 0) * 64 + lane] + ldsR[(rdbase + 1) * 64 + lane]
                              + ldsR[(rdbase + 2) * 64 + lane] + ldsR[(rdbase + 3) * 64 + lane];
                #pragma unroll
                for (int r = 0; r < 4; ++r) {
                    const int br = rowbase + 16 + eroff + r;
                    hd[(size_t)br * HID + ecol] =
                        (_Float16)fast_tanh(s[r] + xv[r] * wxc + bbc);
                }
                asm volatile("s_waitcnt vmcnt(0)" ::: "memory");
                if (lane == 0)
                    __hip_atomic_fetch_add(myflgB, 1u, __ATOMIC_RELAXED, __HIP_MEMORY_SCOPE_WORKGROUP);
            }
        }
    }

    // final release: both sub-batches' t=511 stores visible, then L1 inv
    {
        const unsigned tgt = 4u * (unsigned)SEQL;
        unsigned v;
        do {
            v = __hip_atomic_load(pollA, __ATOMIC_RELAXED, __HIP_MEMORY_SCOPE_AGENT);
        } while (!__all((int)(v >= tgt)));
        do {
            v = __hip_atomic_load(pollB, __ATOMIC_RELAXED, __HIP_MEMORY_SCOPE_AGENT);
        } while (!__all((int)(v >= tgt)));
    }
    asm volatile("buffer_inv sc0" ::: "memory");

    // ---- projection: p = h_last @ wph.T + bp (member m -> row rowbase+m) ----
    const int brow = rowbase + m;
    const _Float16* hp = h1 + (size_t)brow * HID + lane * 32;
    for (int c = j; c < NCLS; c += 8) {
        const float* wp = wph + (size_t)c * HID + lane * 32;
        float psum = 0.f;
        #pragma unroll
        for (int i = 0; i < 32; ++i) psum += (float)hp[i] * wp[i];
        #pragma unroll
        for (int off = 32; off >= 1; off >>= 1) psum += __shfl_xor(psum, off, 64);
        if (lane == 0) out[brow * NCLS + c] = psum + bp[c];
    }
}

extern "C" void kernel_launch(void* const* d_in, const int* in_sizes, int n_in,
                              void* d_out, int out_size, void* d_ws, size_t ws_size,
                              hipStream_t stream) {
    const float* x   = (const float*)d_in[0];
    const float* whx = (const float*)d_in[1];
    const float* whh = (const float*)d_in[2];
    const float* bh  = (const float*)d_in[3];
    const float* wph = (const float*)d_in[4];
    const float* bp  = (const float*)d_in[5];
    float* out = (float*)d_out;

    char* ws = (char*)d_ws;
    _Float16* Wp  = (_Float16*)ws;                         // 8 MiB packed whh fp16 (P + R)
    _Float16* h0  = (_Float16*)(ws + (size_t)(8u << 20));  // 1 MiB  h buffer A
    _Float16* h1  = (_Float16*)(ws + (size_t)(9u << 20));  // 1 MiB  h buffer B
    unsigned* ctr = (unsigned*)(ws + (size_t)(10u << 20)); // 68 KiB alloc + 2x flags

    hipMemsetAsync(ctr, 0, (512 + 2 * 8 * 1024) * sizeof(unsigned), stream);
    pack_w_kernel<<<dim3(2048), dim3(256), 0, stream>>>(whh, Wp);

    void* args[] = { (void*)&x, (void*)&whx, (void*)&Wp, (void*)&bh, (void*)&wph,
                     (void*)&bp, (void*)&h0, (void*)&h1, (void*)&ctr, (void*)&out };
    hipLaunchCooperativeKernel((const void*)rnn_main, dim3(256), dim3(512),
                               args, 0, stream);
}